// Round 16
// baseline (1128.776 us; speedup 1.0000x reference)
//
#include <hip/hip_runtime.h>
#include <hip/hip_bf16.h>

#define NUM_E 64
#define KTOP 8
#define CAP 512
#define TT 2048
#define DD 2048
#define HH 1024

#define BK 32
#define LDSK 36  // B rows 72B: b64 classes at 4-lane/bank minimum

typedef __attribute__((ext_vector_type(4))) float f4v;
typedef __attribute__((ext_vector_type(2))) float f2v;
typedef __attribute__((ext_vector_type(8))) short bf16x8;
typedef __attribute__((ext_vector_type(4))) short bf16x4;

static __device__ __forceinline__ short f2bf(float f) {
    __bf16 b = (__bf16)f;
    return __builtin_bit_cast(short, b);
}
static __device__ __forceinline__ float bf2f(ushort u) {
    unsigned int x = ((unsigned int)u) << 16;
    return __builtin_bit_cast(float, x);
}
static __device__ __forceinline__ int imin(int a, int b) { return a < b ? a : b; }

static __device__ __forceinline__ void load_lds16(const ushort* g, ushort* l) {
    __builtin_amdgcn_global_load_lds(
        (const __attribute__((address_space(1))) unsigned int*)g,
        (__attribute__((address_space(3))) unsigned int*)l, 16, 0, 0);
}

static __device__ __forceinline__ void pipe_barrier() {
    asm volatile("s_waitcnt lgkmcnt(0)" ::: "memory");
    __builtin_amdgcn_s_barrier();
}

// ---------------- init: zero counts ----------------
__global__ __launch_bounds__(64) void k_init(int* __restrict__ counts) {
    counts[threadIdx.x] = 0;
}

// ---------------- prep: x f32 -> bf16 (stored in out[] region) ----------------
__global__ __launch_bounds__(256) void k_prep(const float* __restrict__ x,
                                              ushort* __restrict__ xbf) {
    int idx = blockIdx.x * 256 + threadIdx.x;
    size_t i8 = (size_t)idx * 8;
    f4v v0 = *(const f4v*)(x + i8);
    f4v v1 = *(const f4v*)(x + i8 + 4);
    bf16x8 o = {f2bf(v0[0]), f2bf(v0[1]), f2bf(v0[2]), f2bf(v0[3]),
                f2bf(v1[0]), f2bf(v1[1]), f2bf(v1[2]), f2bf(v1[3])};
    *(bf16x8*)(xbf + i8) = o;
}

// ---------------- zero out[] (atomic-fallback path only) ----------------
__global__ __launch_bounds__(256) void k_zero(float* __restrict__ out) {
    int idx = blockIdx.x * 256 + threadIdx.x;
    f4v z = {0.f, 0.f, 0.f, 0.f};
    ((f4v*)out)[idx] = z;
}

// ---------------- router ----------------
#define RTOK 8
__global__ __launch_bounds__(256) void k_router(const float* __restrict__ x,
                                                const float* __restrict__ gw,
                                                float* __restrict__ logits) {
    __shared__ float xs[RTOK][512];
    const int tid = threadIdx.x;
    const int lane = tid & 63, wid = tid >> 6;
    const int t0 = blockIdx.x * RTOK;
    float a0 = 0.f, a1 = 0.f;
    for (int c = 0; c < DD / 512; ++c) {
        __syncthreads();
#pragma unroll
        for (int u = tid * 4; u < RTOK * 512; u += 1024) {
            int r = u >> 9, col = u & 511;
            *(f4v*)&xs[r][col] = *(const f4v*)&x[(size_t)(t0 + r) * DD + c * 512 + col];
        }
        __syncthreads();
        const float* gcol = gw + (size_t)c * 512 * NUM_E + lane;
#pragma unroll 8
        for (int d = 0; d < 512; ++d) {
            float g = gcol[(size_t)d * NUM_E];
            a0 = fmaf(xs[wid * 2 + 0][d], g, a0);
            a1 = fmaf(xs[wid * 2 + 1][d], g, a1);
        }
    }
    logits[(size_t)(t0 + wid * 2 + 0) * NUM_E + lane] = a0;
    logits[(size_t)(t0 + wid * 2 + 1) * NUM_E + lane] = a1;
}

// ---------------- topk + dispatch (also builds token->slot map) ----------------
__global__ __launch_bounds__(256) void k_topk(const float* __restrict__ logits,
                                              int* __restrict__ counts,
                                              int* __restrict__ slot_token,
                                              float* __restrict__ slot_wt,
                                              int* __restrict__ tok_slot) {
    int lane = threadIdx.x & 63, wid = threadIdx.x >> 6;
    int t = blockIdx.x * 4 + wid;
    float l = logits[(size_t)t * NUM_E + lane];
    float m = l;
#pragma unroll
    for (int off = 32; off; off >>= 1) m = fmaxf(m, __shfl_xor(m, off));
    float ex = __expf(l - m);
    float s = ex;
#pragma unroll
    for (int off = 32; off; off >>= 1) s += __shfl_xor(s, off);
    float p = ex / s;
#pragma unroll
    for (int k = 0; k < KTOP; ++k) {
        float v = p;
        int i = lane;
#pragma unroll
        for (int off = 32; off; off >>= 1) {
            float v2 = __shfl_xor(v, off);
            int i2 = __shfl_xor(i, off);
            if (v2 > v || (v2 == v && i2 < i)) { v = v2; i = i2; }
        }
        if (lane == i) {
            int pos = atomicAdd(&counts[i], 1);
            if (pos < CAP) {
                int slot = i * CAP + pos;
                slot_token[slot] = t;
                slot_wt[slot] = v;
                tok_slot[t * KTOP + k] = slot;
            } else {
                tok_slot[t * KTOP + k] = -1;
            }
            p = -1.0f;
        }
    }
}

// ================= gate+up fused GEMM + SwiGLU -> h =================
// BM=256, BN=64, BK=32; 512 threads = 8 waves (4m x 2n); wave 64x32 dual acc.
// A: triple-buffered global_load_lds DMA (2-phase cover), src-octet XOR.
// B: dual reg banks (2-phase cover) -> LDSK=36 dbuf. vmcnt(6)/phase keeps only
// this phase's {2 DMA + 4 B-loads} in flight; drains everything older.
__global__ __launch_bounds__(512, 2) void k_gateup(
    const ushort* __restrict__ xbf, const float* __restrict__ wg, const float* __restrict__ wu,
    const int* __restrict__ counts, const int* __restrict__ slot_token,
    const float* __restrict__ slot_wt, ushort* __restrict__ hbuf) {
    const int e = blockIdx.z;
    int count = counts[e];
    if (count > CAP) count = CAP;
    const int mrow0 = blockIdx.y * 256;
    if (mrow0 >= count) return;
    const int ncol0 = blockIdx.x * 64;
    const int tid = threadIdx.x;
    const int lane = tid & 63, wid = tid >> 6;
    const int wm = wid >> 1, wn = wid & 1;
    const int lrow = lane & 15, g4 = lane >> 4;

    __shared__ ushort As0[256 * 32], As1[256 * 32], As2[256 * 32];  // 16KB each
    __shared__ ushort Bg0[64 * LDSK], Bg1[64 * LDSK];
    __shared__ ushort Bu0[64 * LDSK], Bu1[64 * LDSK];

    // A DMA: wave stages rows [wid*32, wid*32+32); 2 instrs x 16 rows.
    const ushort* aglb[2];
#pragma unroll
    for (int i = 0; i < 2; ++i) {
        int rl = wid * 32 + i * 16 + (lane >> 2);
        int rg = imin(mrow0 + rl, count - 1);
        int tok = slot_token[e * CAP + rg];
        aglb[i] = xbf + (size_t)tok * DD + (((lane & 3) ^ ((lane >> 2) & 3)) * 8);
    }
    // B staging: tid&256 selects wg/wu; unit = 2 cols x 4 k (f2v loads).
    const int bidx = tid & 255;
    const int col0 = (bidx & 31) * 2;
    const int bkq = (bidx >> 5) * 4;
    const float* bptr = ((tid & 256) ? wu : wg) + ((size_t)e * DD + bkq) * HH + ncol0 + col0;
    ushort* myB0 = (tid & 256) ? Bu0 : Bg0;
    ushort* myB1 = (tid & 256) ? Bu1 : Bg1;

    f2v sbX[4], sbY[4];
    f4v accg[4][2], accu[4][2];
    const f4v fz = {0.f, 0.f, 0.f, 0.f};
#pragma unroll
    for (int m = 0; m < 4; ++m)
#pragma unroll
        for (int n = 0; n < 2; ++n) { accg[m][n] = fz; accu[m][n] = fz; }

#define GU_ADMA(ASB, KO) { \
    load_lds16(aglb[0] + (KO), &ASB[(wid * 32 + 0) * 32]); \
    load_lds16(aglb[1] + (KO), &ASB[(wid * 32 + 16) * 32]); }

#define GU_BLOAD(SB, KO) { \
    _Pragma("unroll") for (int j_ = 0; j_ < 4; ++j_) \
        SB[j_] = *(const f2v*)(bptr + (size_t)((KO) + j_) * HH); }

#define GU_BWRITE(SB, BD) { \
    _Pragma("unroll") for (int c_ = 0; c_ < 2; ++c_) { \
        bf16x4 v_ = {f2bf(SB[0][c_]), f2bf(SB[1][c_]), f2bf(SB[2][c_]), f2bf(SB[3][c_])}; \
        *(bf16x4*)&BD[(col0 + c_) * LDSK + bkq] = v_; } }

#define GU_FM(AS, BG, BU) { \
    bf16x8 af_[4]; \
    _Pragma("unroll") for (int m_ = 0; m_ < 4; ++m_) { \
        const int row_ = wm * 64 + m_ * 16 + lrow; \
        af_[m_] = *(const bf16x8*)&AS[row_ * 32 + ((g4 ^ (row_ & 3)) * 8)]; } \
    _Pragma("unroll") for (int n_ = 0; n_ < 2; ++n_) { \
        const int c_ = (wn * 32 + n_ * 16 + lrow) * LDSK + g4 * 8; \
        union { bf16x8 v8; bf16x4 v4[2]; } ug_, uu_; \
        ug_.v4[0] = *(const bf16x4*)&BG[c_]; ug_.v4[1] = *(const bf16x4*)&BG[c_ + 4]; \
        uu_.v4[0] = *(const bf16x4*)&BU[c_]; uu_.v4[1] = *(const bf16x4*)&BU[c_ + 4]; \
        _Pragma("unroll") for (int m_ = 0; m_ < 4; ++m_) { \
            accg[m_][n_] = __builtin_amdgcn_mfma_f32_16x16x32_bf16(af_[m_], ug_.v8, accg[m_][n_], 0, 0, 0); \
            accu[m_][n_] = __builtin_amdgcn_mfma_f32_16x16x32_bf16(af_[m_], uu_.v8, accu[m_][n_], 0, 0, 0); } } }

// phase t: consume As[t%3], B lds[t&1]; DMA -> As[(t+2)%3]; B bank[(t+1)&1]
// writes lds[(t+1)&1] then reloads <- k(t+3). vmcnt(6) = 2 DMA + 4 B-loads.
#define GU_PH(AC, AD, BGC, BUC, BGD, BUD, SB, KD, KB) { \
    GU_ADMA(AD, KD); \
    __builtin_amdgcn_sched_barrier(0); \
    GU_BWRITE(SB, BGD); \
    GU_BLOAD(SB, KB); \
    __builtin_amdgcn_sched_barrier(0); \
    GU_FM(AC, BGC, BUC); \
    asm volatile("s_waitcnt vmcnt(6)" ::: "memory"); \
    __builtin_amdgcn_sched_barrier(0); \
    pipe_barrier(); }

    const int NK = DD / BK;  // 64
#define GKO(T) (imin((T), NK - 1) * BK)

    // prologue: A(t0),A(t1) DMA; B(t0)->lds0; banks: Y<-B(t1), X<-B(t2)
    GU_ADMA(As0, 0);
    GU_ADMA(As1, BK);
    __builtin_amdgcn_sched_barrier(0);
    GU_BLOAD(sbX, 0);
    GU_BWRITE(sbX, myB0);     // auto-wait drains DMAs + B(t0) loads
    GU_BLOAD(sbY, BK);
    GU_BLOAD(sbX, 2 * BK);
    pipe_barrier();

    for (int kt = 0; kt < 60; kt += 6) {
        GU_PH(As0, As2, Bg0, Bu0, myB1, 0, sbY, GKO(kt + 2), GKO(kt + 3));
        GU_PH(As1, As0, Bg1, Bu1, myB0, 0, sbX, GKO(kt + 3), GKO(kt + 4));
        GU_PH(As2, As1, Bg0, Bu0, myB1, 0, sbY, GKO(kt + 4), GKO(kt + 5));
        GU_PH(As0, As2, Bg1, Bu1, myB0, 0, sbX, GKO(kt + 5), GKO(kt + 6));
        GU_PH(As1, As0, Bg0, Bu0, myB1, 0, sbY, GKO(kt + 6), GKO(kt + 7));
        GU_PH(As2, As1, Bg1, Bu1, myB0, 0, sbX, GKO(kt + 7), GKO(kt + 8));
    }
    // tail phases t = 60..63 (60%3=0 -> same rotation as loop head)
    GU_PH(As0, As2, Bg0, Bu0, myB1, 0, sbY, GKO(62), GKO(63));
    GU_PH(As1, As0, Bg1, Bu1, myB0, 0, sbX, GKO(63), GKO(63));
    GU_PH(As2, As1, Bg0, Bu0, myB1, 0, sbY, GKO(63), GKO(63));
    GU_PH(As0, As2, Bg1, Bu1, myB0, 0, sbX, GKO(63), GKO(63));

    // epilogue: h = silu(g)*u * gate-weight, bf16
#pragma unroll
    for (int m = 0; m < 4; ++m) {
#pragma unroll
        for (int r = 0; r < 4; ++r) {
            int row = mrow0 + wm * 64 + m * 16 + g4 * 4 + r;
            if (row < count) {
                float wgt = slot_wt[e * CAP + row];
                size_t base = (size_t)(e * CAP + row) * HH + ncol0 + wn * 32;
#pragma unroll
                for (int n = 0; n < 2; ++n) {
                    float g = accg[m][n][r], uv = accu[m][n][r];
                    float hv = (g / (1.f + __expf(-g))) * uv * wgt;
                    hbuf[base + n * 16 + lrow] = (ushort)f2bf(hv);
                }
            }
        }
    }
}

// ================= down GEMM -> ybuf (or atomic out) =================
// BM=256, BN=128, BK=32; 512 threads = 8 waves (4m x 2n); wave 64x64.
__global__ __launch_bounds__(512, 2) void k_down(
    const ushort* __restrict__ hbuf, const float* __restrict__ wd,
    const int* __restrict__ counts, const int* __restrict__ slot_token,
    float* __restrict__ out, ushort* __restrict__ ybf, const int combine) {
    const int e = blockIdx.z;
    int count = counts[e];
    if (count > CAP) count = CAP;
    const int mrow0 = blockIdx.y * 256;
    if (mrow0 >= count) return;
    const int ncol0 = blockIdx.x * 128;
    const int tid = threadIdx.x;
    const int lane = tid & 63, wid = tid >> 6;
    const int wm = wid >> 1, wn = wid & 1;
    const int lrow = lane & 15, g4 = lane >> 4;

    __shared__ ushort As0[256 * 32], As1[256 * 32], As2[256 * 32];
    __shared__ ushort Bs0[128 * LDSK], Bs1[128 * LDSK];

    const ushort* aglb[2];
#pragma unroll
    for (int i = 0; i < 2; ++i) {
        int rl = wid * 32 + i * 16 + (lane >> 2);
        int rg = imin(mrow0 + rl, count - 1);
        aglb[i] = hbuf + (size_t)(e * CAP + rg) * HH + (((lane & 3) ^ ((lane >> 2) & 3)) * 8);
    }
    // B: unit = 2 cols x 4 k (f2v): col0=(tid&63)*2, kq=((tid>>6)&7)*4
    const int col0 = (tid & 63) * 2;
    const int bkq = ((tid >> 6) & 7) * 4;
    const float* bptr = wd + ((size_t)e * HH + bkq) * DD + ncol0 + col0;

    f2v sbX[4], sbY[4];
    f4v acc[4][4];
    const f4v fz = {0.f, 0.f, 0.f, 0.f};
#pragma unroll
    for (int m = 0; m < 4; ++m)
#pragma unroll
        for (int n = 0; n < 4; ++n) acc[m][n] = fz;

#define DN_ADMA(ASB, KO) { \
    load_lds16(aglb[0] + (KO), &ASB[(wid * 32 + 0) * 32]); \
    load_lds16(aglb[1] + (KO), &ASB[(wid * 32 + 16) * 32]); }

#define DN_BLOAD(SB, KO) { \
    _Pragma("unroll") for (int j_ = 0; j_ < 4; ++j_) \
        SB[j_] = *(const f2v*)(bptr + (size_t)((KO) + j_) * DD); }

#define DN_BWRITE(SB, BD) { \
    _Pragma("unroll") for (int c_ = 0; c_ < 2; ++c_) { \
        bf16x4 v_ = {f2bf(SB[0][c_]), f2bf(SB[1][c_]), f2bf(SB[2][c_]), f2bf(SB[3][c_])}; \
        *(bf16x4*)&BD[(col0 + c_) * LDSK + bkq] = v_; } }

#define DN_FM(AS, BS) { \
    bf16x8 af_[4]; \
    _Pragma("unroll") for (int m_ = 0; m_ < 4; ++m_) { \
        const int row_ = wm * 64 + m_ * 16 + lrow; \
        af_[m_] = *(const bf16x8*)&AS[row_ * 32 + ((g4 ^ (row_ & 3)) * 8)]; } \
    _Pragma("unroll") for (int n_ = 0; n_ < 4; ++n_) { \
        const int c_ = (wn * 64 + n_ * 16 + lrow) * LDSK + g4 * 8; \
        union { bf16x8 v8; bf16x4 v4[2]; } ub_; \
        ub_.v4[0] = *(const bf16x4*)&BS[c_]; ub_.v4[1] = *(const bf16x4*)&BS[c_ + 4]; \
        _Pragma("unroll") for (int m_ = 0; m_ < 4; ++m_) \
            acc[m_][n_] = __builtin_amdgcn_mfma_f32_16x16x32_bf16(af_[m_], ub_.v8, acc[m_][n_], 0, 0, 0); } }

#define DN_PH(AC, AD, BC, BD, SB, KD, KB) { \
    DN_ADMA(AD, KD); \
    __builtin_amdgcn_sched_barrier(0); \
    DN_BWRITE(SB, BD); \
    DN_BLOAD(SB, KB); \
    __builtin_amdgcn_sched_barrier(0); \
    DN_FM(AC, BC); \
    asm volatile("s_waitcnt vmcnt(6)" ::: "memory"); \
    __builtin_amdgcn_sched_barrier(0); \
    pipe_barrier(); }

    const int NKD = HH / BK;  // 32
#define DKO(T) (imin((T), NKD - 1) * BK)

    DN_ADMA(As0, 0);
    DN_ADMA(As1, BK);
    __builtin_amdgcn_sched_barrier(0);
    DN_BLOAD(sbX, 0);
    DN_BWRITE(sbX, Bs0);
    DN_BLOAD(sbY, BK);
    DN_BLOAD(sbX, 2 * BK);
    pipe_barrier();

    for (int kt = 0; kt < 30; kt += 6) {
        DN_PH(As0, As2, Bs0, Bs1, sbY, DKO(kt + 2), DKO(kt + 3));
        DN_PH(As1, As0, Bs1, Bs0, sbX, DKO(kt + 3), DKO(kt + 4));
        DN_PH(As2, As1, Bs0, Bs1, sbY, DKO(kt + 4), DKO(kt + 5));
        DN_PH(As0, As2, Bs1, Bs0, sbX, DKO(kt + 5), DKO(kt + 6));
        DN_PH(As1, As0, Bs0, Bs1, sbY, DKO(kt + 6), DKO(kt + 7));
        DN_PH(As2, As1, Bs1, Bs0, sbX, DKO(kt + 7), DKO(kt + 8));
    }
    // tail phases t = 30, 31
    DN_PH(As0, As2, Bs0, Bs1, sbY, DKO(31), DKO(31));
    DN_PH(As1, As0, Bs1, Bs0, sbX, DKO(31), DKO(31));

    if (combine) {
#pragma unroll
        for (int m = 0; m < 4; ++m) {
#pragma unroll
            for (int r = 0; r < 4; ++r) {
                int row = mrow0 + wm * 64 + m * 16 + g4 * 4 + r;
                if (row < count) {
                    size_t base = (size_t)(e * CAP + row) * DD + ncol0 + wn * 64;
#pragma unroll
                    for (int n = 0; n < 4; ++n)
                        ybf[base + n * 16 + lrow] = (ushort)f2bf(acc[m][n][r]);
                }
            }
        }
    } else {
#pragma unroll
        for (int m = 0; m < 4; ++m) {
#pragma unroll
            for (int r = 0; r < 4; ++r) {
                int row = mrow0 + wm * 64 + m * 16 + g4 * 4 + r;
                if (row < count) {
                    int tok = slot_token[e * CAP + row];
                    float* obase = out + (size_t)tok * DD + ncol0 + wn * 64;
#pragma unroll
                    for (int n = 0; n < 4; ++n) atomicAdd(obase + n * 16 + lrow, acc[m][n][r]);
                }
            }
        }
    }
}

// ---------------- combine: out[t] = sum_k ybf[tok_slot[t,k]] ----------------
__global__ __launch_bounds__(256) void k_combine(const ushort* __restrict__ ybf,
                                                 const int* __restrict__ tok_slot,
                                                 float* __restrict__ out) {
    const int t = blockIdx.x;
    const int d0 = threadIdx.x * 8;
    float acc[8];
#pragma unroll
    for (int j = 0; j < 8; ++j) acc[j] = 0.f;
#pragma unroll
    for (int k = 0; k < KTOP; ++k) {
        int s = tok_slot[t * KTOP + k];
        if (s >= 0) {
            bf16x8 v = *(const bf16x8*)&ybf[(size_t)s * DD + d0];
#pragma unroll
            for (int j = 0; j < 8; ++j) acc[j] += bf2f((ushort)v[j]);
        }
    }
    f4v o0 = {acc[0], acc[1], acc[2], acc[3]};
    f4v o1 = {acc[4], acc[5], acc[6], acc[7]};
    *(f4v*)&out[(size_t)t * DD + d0] = o0;
    *(f4v*)&out[(size_t)t * DD + d0 + 4] = o1;
}

extern "C" void kernel_launch(void* const* d_in, const int* in_sizes, int n_in,
                              void* d_out, int out_size, void* d_ws, size_t ws_size,
                              hipStream_t stream) {
    const float* x = (const float*)d_in[0];       // [1,2048,2048]
    const float* gw = (const float*)d_in[1];      // [2048,64]
    const float* wg = (const float*)d_in[2];      // [64,2048,1024]
    const float* wu = (const float*)d_in[3];      // [64,2048,1024]
    const float* wd = (const float*)d_in[4];      // [64,1024,2048]
    float* out = (float*)d_out;                   // [T*D] then logits [T*E]
    float* logits = out + (size_t)TT * DD;

    char* ws = (char*)d_ws;
    int* counts = (int*)ws;                                        // 1 KB
    int* slot_token = (int*)(ws + 1024);                           // 128 KB
    float* slot_wt = (float*)(ws + 1024 + 131072);                 // 128 KB
    int* tok_slot = (int*)(ws + 1024 + 262144);                    // 64 KB
    ushort* hbuf = (ushort*)(ws + 1024 + 262144 + 65536);          // 64 MB
    ushort* ybf = (ushort*)(ws + 328704 + 67108864);               // 128 MB
    const size_t WS_NEED = 328704ULL + 67108864ULL + 134217728ULL; // ~202 MB
    const int combine = (ws_size >= WS_NEED) ? 1 : 0;
    ushort* xbf = (ushort*)out;  // 8 MB bf16 copy of x in out[] region

    k_init<<<1, 64, 0, stream>>>(counts);
    k_prep<<<(TT * DD / 8) / 256, 256, 0, stream>>>(x, xbf);
    k_router<<<TT / RTOK, 256, 0, stream>>>(x, gw, logits);
    k_topk<<<TT / 4, 256, 0, stream>>>(logits, counts, slot_token, slot_wt, tok_slot);
    k_gateup<<<dim3(HH / 64, CAP / 256, NUM_E), 512, 0, stream>>>(xbf, wg, wu, counts, slot_token, slot_wt, hbuf);
    if (!combine) k_zero<<<(TT * DD / 4) / 256, 256, 0, stream>>>(out);
    k_down<<<dim3(DD / 128, CAP / 256, NUM_E), 512, 0, stream>>>(hbuf, wd, counts, slot_token, out, ybf, combine);
    if (combine) k_combine<<<TT, 256, 0, stream>>>(ybf, tok_slot, out);
}